// Round 22
// baseline (41.843 us; speedup 1.0000x reference)
//
#include <hip/hip_runtime.h>

// STN forward, R22: R21 pushed along the amplification/TLP curve.
// Tile 8x8x32 (d,h,w), NT=512, 4 vox/thread (2h x 2w). Staged region
// 15x15x40 -> 4.4 floats/voxel (R21: 6.4, R19: 9.45). LDS = 225 rows x
// 44 dwords = 39,600B -> 4 blocks/CU (158KB) = 32 waves. Two passes over
// one buffer; staging = 4 uniform global_load_lds rounds + 427-granule
// partial-wave load->ds_write tail; gather = 16 ds_read2_b32 per thread
// per pass batched behind ONE lgkmcnt(0)+sched_barrier(0). Weights
// recomputed per pass from 12 persisted coord regs (VGPR <= 64 target).

constexpr int B = 2, C = 2, D = 128, H = 128, W = 128;
constexpr int HW  = H * W;
constexpr int DHW = D * HW;
constexpr int RD = 15, RH = 15;              // region extents (halo 3)
constexpr int ROWD = 44;                     // LDS row dwords (40 used + 4 pad)
constexpr int GPR = 11;                      // granules per row
constexpr int NROWR = RD * RH;               // 225 real rows
constexpr int NGR = NROWR * GPR;             // 2475 real granules
constexpr int NT = 512;
constexpr int TAILN = NGR - 4 * NT;          // 427 tail granules
constexpr int ROW_B = ROWD * 4;              // 176 B
constexpr int PLANE_B = RH * ROW_B;          // 2640 B

typedef float v2f __attribute__((ext_vector_type(2)));

__device__ __forceinline__ void gload_lds16(const float* g, float* l) {
    __builtin_amdgcn_global_load_lds(
        (const __attribute__((address_space(1))) void*)g,
        (__attribute__((address_space(3))) void*)l, 16, 0, 0);
}

__global__ __launch_bounds__(NT) void stn_kernel(
    const float* __restrict__ image,
    const float* __restrict__ ddf,
    float* __restrict__ out)
{
    __shared__ float smem[NROWR * ROWD];     // 39,600 B

    // XCD-contiguous swizzle (2048 blocks, %8==0 -> bijective)
    const int bid = blockIdx.x;
    const int cpx = gridDim.x >> 3;          // 256
    const int blk = (bid & 7) * cpx + (bid >> 3);

    const int b  = blk >> 10;                // 1024 tiles/batch: 16d x 16h x 4w
    const int tb = blk & 1023;
    const int t0d = (tb >> 6) * 8;
    const int t0h = ((tb >> 2) & 15) * 8;
    const int t0w = (tb & 3) * 32;
    const int lo_d = max(t0d - 3, 0), lo_h = max(t0h - 3, 0);
    const int lo_w = max(t0w - 4, 0);        // 4-aligned
    const int hi_d = min(lo_d + RD - 1, D - 1);
    const int hi_h = min(lo_h + RH - 1, H - 1);
    const int hi_w = min(lo_w + 39, W - 1);  // cols 40..43 are pad
    const float* imgb = image + (size_t)b * C * DHW;
    const int tid = threadIdx.x;
    const unsigned lds0 =
        (unsigned)(uintptr_t)(__attribute__((address_space(3))) void*)&smem[0];

    // 4 voxels/thread: (d_, h0/h0+4, w2/w2+1)
    const int dl = tid >> 6, hl = (tid >> 4) & 3, wi = tid & 15;
    const int d_ = t0d + dl;
    const int h0_ = t0h + hl;
    const int w2 = t0w + wi * 2;
    const int sidx0 = d_ * HW + h0_ * W + w2;
    const int sidx1 = sidx0 + 4 * W;         // h0 + 4

    // ---- ddf loads FIRST ----
    const float* dp = ddf + (size_t)b * 3 * DHW;
    float2 vd0 = *reinterpret_cast<const float2*>(dp + sidx0);
    float2 vd1 = *reinterpret_cast<const float2*>(dp + sidx1);
    float2 vh0 = *reinterpret_cast<const float2*>(dp + DHW + sidx0);
    float2 vh1 = *reinterpret_cast<const float2*>(dp + DHW + sidx1);
    float2 vw0 = *reinterpret_cast<const float2*>(dp + 2 * DHW + sidx0);
    float2 vw1 = *reinterpret_cast<const float2*>(dp + 2 * DHW + sidx1);
    asm volatile("" ::: "memory");

    // granule g -> global offset (row/w overhang clamp-dup, never read)
    auto gsrc_off = [&](int g) {
        int row = g / GPR;
        int rw  = (g - row * GPR) * 4;
        int rc  = min(row, NROWR - 1);
        int rd  = rc / RH;
        int rh  = rc - rd * RH;
        return min(lo_d + rd, D - 1) * HW + min(lo_h + rh, H - 1) * W
             + min(lo_w + rw, W - 4);
    };

    auto issue_stage = [&](const float* src) {
#pragma unroll
        for (int i = 0; i < 4; ++i) {        // 4 uniform rounds
            int g = tid + i * NT;            // < 2048 < NGR
            gload_lds16(src + gsrc_off(g), &smem[g * 4]);
        }
        if (tid < TAILN) {                   // partial-wave-safe ds_write tail
            int g = tid + 4 * NT;            // 2048..2474
            float4 v = *reinterpret_cast<const float4*>(src + gsrc_off(g));
            *reinterpret_cast<float4*>(&smem[g * 4]) = v;
        }
    };

    issue_stage(imgb);                       // ch0 in flight
    asm volatile("" ::: "memory");

    // clamped coords, 4 voxels (12 VGPR, persisted across both passes)
    float cds[4], chs[4], cws[4];
    {
        const float ad[4] = {vd0.x, vd0.y, vd1.x, vd1.y};
        const float ah[4] = {vh0.x, vh0.y, vh1.x, vh1.y};
        const float aw[4] = {vw0.x, vw0.y, vw1.x, vw1.y};
#pragma unroll
        for (int v = 0; v < 4; ++v) {
            int hv = h0_ + (v >> 1) * 4;
            int wv = w2 + (v & 1);
            cds[v] = fminf(fmaxf((float)d_ + ad[v], 0.0f), (float)(D - 1));
            chs[v] = fminf(fmaxf((float)hv + ah[v], 0.0f), (float)(H - 1));
            cws[v] = fminf(fmaxf((float)wv + aw[v], 0.0f), (float)(W - 1));
        }
    }

    // one pass: weights/addr recomputed, 16 ds_read2_b32 batched -> one
    // wait -> FMAs; rare exact fixup; 2x float2 store.
    auto do_pass = [&](const float* gimg, float* obase) {
        unsigned a0[4];
        float W00[4], W01[4], W10[4], W11[4], GD[4], FD[4];
        int fb = 0;
#pragma unroll
        for (int v = 0; v < 4; ++v) {
            float cd = cds[v], ch = chs[v], cw = cws[v];
            float d0f = floorf(cd), h0f = floorf(ch), w0f = floorf(cw);
            float fd = cd - d0f, fh = ch - h0f, fw = cw - w0f;
            int d0 = (int)d0f, h0 = (int)h0f, w0 = (int)w0f;
            bool bad = (d0 < lo_d) | (d0 + 1 > hi_d)
                     | (h0 < lo_h) | (h0 + 1 > hi_h)
                     | (w0 < lo_w) | (w0 + 1 > hi_w);
            fb |= (int)bad << v;
            float gh = 1.0f - fh, gw = 1.0f - fw;
            W00[v] = gh * gw; W01[v] = gh * fw;
            W10[v] = fh * gw; W11[v] = fh * fw;
            GD[v] = 1.0f - fd; FD[v] = fd;
            int row = (d0 - lo_d) * RH + (h0 - lo_h);
            a0[v] = lds0 + (unsigned)(row * ROW_B + (w0 - lo_w) * 4);
        }
        v2f r00[4], r01[4], r10[4], r11[4];
#pragma unroll
        for (int v = 0; v < 4; ++v) {
            unsigned a1 = a0[v] + PLANE_B;
            asm volatile("ds_read2_b32 %0, %1 offset0:0 offset1:1"
                         : "=v"(r00[v]) : "v"(a0[v]));
            asm volatile("ds_read2_b32 %0, %1 offset0:44 offset1:45"
                         : "=v"(r01[v]) : "v"(a0[v]));
            asm volatile("ds_read2_b32 %0, %1 offset0:0 offset1:1"
                         : "=v"(r10[v]) : "v"(a1));
            asm volatile("ds_read2_b32 %0, %1 offset0:44 offset1:45"
                         : "=v"(r11[v]) : "v"(a1));
        }
        asm volatile("s_waitcnt lgkmcnt(0)" ::: "memory");
        __builtin_amdgcn_sched_barrier(0);

        float acc[4];
#pragma unroll
        for (int v = 0; v < 4; ++v) {
            float p0 = r00[v].x * W00[v] + r00[v].y * W01[v]
                     + r01[v].x * W10[v] + r01[v].y * W11[v];
            float p1 = r10[v].x * W00[v] + r10[v].y * W01[v]
                     + r11[v].x * W10[v] + r11[v].y * W11[v];
            acc[v] = GD[v] * p0 + FD[v] * p1;
        }
        if (fb) {                            // rare: exact global recompute
#pragma unroll
            for (int v = 0; v < 4; ++v) {
                if (fb & (1 << v)) {
                    float cd = cds[v], ch = chs[v], cw = cws[v];
                    float d0f = floorf(cd), h0f = floorf(ch), w0f = floorf(cw);
                    float fd = cd - d0f, fh = ch - h0f, fw = cw - w0f;
                    int d0 = (int)d0f, h0 = (int)h0f, w0 = (int)w0f;
                    int d1 = min(d0 + 1, D - 1);
                    int h1 = min(h0 + 1, H - 1);
                    int w1 = min(w0 + 1, W - 1);
                    float gd = 1.0f - fd, gh = 1.0f - fh, gw = 1.0f - fw;
                    float w00 = gh * gw, w01 = gh * fw, w10 = fh * gw, w11 = fh * fw;
                    int o00 = d0 * HW + h0 * W, o01 = d0 * HW + h1 * W;
                    int o10 = d1 * HW + h0 * W, o11 = d1 * HW + h1 * W;
                    float q0 = gimg[o00 + w0] * w00 + gimg[o00 + w1] * w01
                             + gimg[o01 + w0] * w10 + gimg[o01 + w1] * w11;
                    float q1 = gimg[o10 + w0] * w00 + gimg[o10 + w1] * w01
                             + gimg[o11 + w0] * w10 + gimg[o11 + w1] * w11;
                    acc[v] = gd * q0 + fd * q1;
                }
            }
        }
        *reinterpret_cast<float2*>(obase + sidx0) = make_float2(acc[0], acc[1]);
        *reinterpret_cast<float2*>(obase + sidx1) = make_float2(acc[2], acc[3]);
    };

    float* outb = out + (size_t)b * C * DHW;

    // ---- pass 0 ----
    asm volatile("s_waitcnt vmcnt(0) lgkmcnt(0)" ::: "memory");  // ch0 staged
    __builtin_amdgcn_s_barrier();
    do_pass(imgb, outb);

    __builtin_amdgcn_s_barrier();                       // ch0 reads done
    asm volatile("" ::: "memory");

    // ---- pass 1 ----
    issue_stage(imgb + DHW);
    asm volatile("s_waitcnt vmcnt(0) lgkmcnt(0)" ::: "memory");  // ch1 staged
    __builtin_amdgcn_s_barrier();
    do_pass(imgb + DHW, outb + DHW);
}

extern "C" void kernel_launch(void* const* d_in, const int* in_sizes, int n_in,
                              void* d_out, int out_size, void* d_ws, size_t ws_size,
                              hipStream_t stream) {
    const float* image = (const float*)d_in[0];
    const float* ddf   = (const float*)d_in[1];
    float* out = (float*)d_out;

    int grid = B * 1024;   // 16d x 16h x 4w tiles of 8x8x32 = 2048 blocks
    stn_kernel<<<grid, NT, 0, stream>>>(image, ddf, out);
}

// Round 23
// 33.600 us; speedup vs baseline: 1.2454x; 1.2454x over previous
//
#include <hip/hip_runtime.h>

// STN forward, R23: R21 structure (2 vox/thread, VGPR~32, 4-block stagger)
// at a better geometry point. Tile 8x8x16 (d,h,w), NT=512 (8d x 8h x 8
// w-pairs). Region 15x15x24 -> 5.27 staged floats/voxel (R21: 6.4), d-halo
// amortized over 8 planes. ROWD=24 (no staged pad), LDS 21,600B -> 4
// blocks/CU = 32 waves. Staging: 2 uniform global_load_lds rounds + 326-
// granule load->ds_write tail. Gather: 8 ds_read2_b32 batched behind one
// lgkmcnt(0)+sched_barrier(0). Rare exact global fixup for |jitter|>halo.

constexpr int B = 2, C = 2, D = 128, H = 128, W = 128;
constexpr int HW  = H * W;
constexpr int DHW = D * HW;
constexpr int RD = 15, RH = 15;              // region extents (halo 3)
constexpr int ROWD = 24;                     // row dwords (w: -4..+19, no pad)
constexpr int GPR = 6;                       // granules per row
constexpr int NROWR = RD * RH;               // 225 rows
constexpr int NGR = NROWR * GPR;             // 1350 granules
constexpr int NT = 512;
constexpr int TAILN = NGR - 2 * NT;          // 326 tail granules
constexpr int ROW_B = ROWD * 4;              // 96 B
constexpr int PLANE_B = RH * ROW_B;          // 1440 B

typedef float v2f __attribute__((ext_vector_type(2)));

__device__ __forceinline__ void gload_lds16(const float* g, float* l) {
    __builtin_amdgcn_global_load_lds(
        (const __attribute__((address_space(1))) void*)g,
        (__attribute__((address_space(3))) void*)l, 16, 0, 0);
}

__global__ __launch_bounds__(NT) void stn_kernel(
    const float* __restrict__ image,
    const float* __restrict__ ddf,
    float* __restrict__ out)
{
    __shared__ float smem[NGR * 4];          // 21,600 B

    // XCD-contiguous swizzle (4096 blocks, %8==0 -> bijective)
    const int bid = blockIdx.x;
    const int cpx = gridDim.x >> 3;          // 512
    const int blk = (bid & 7) * cpx + (bid >> 3);

    const int b  = blk >> 11;                // 2048 tiles/batch: 16d x 16h x 8w
    const int tb = blk & 2047;
    const int t0d = (tb >> 7) * 8;
    const int t0h = ((tb >> 3) & 15) * 8;
    const int t0w = (tb & 7) * 16;
    const int lo_d = max(t0d - 3, 0), lo_h = max(t0h - 3, 0);
    const int lo_w = max(t0w - 4, 0);        // 4-aligned
    const int hi_d = min(lo_d + RD - 1, D - 1);
    const int hi_h = min(lo_h + RH - 1, H - 1);
    const int hi_w = min(lo_w + ROWD - 1, W - 1);
    const float* imgb = image + (size_t)b * C * DHW;
    const int tid = threadIdx.x;
    const unsigned lds0 =
        (unsigned)(uintptr_t)(__attribute__((address_space(3))) void*)&smem[0];

    // 2 voxels/thread: (d_, h_, w2) and (d_, h_, w2+1)
    const int dl = tid >> 6, hl = (tid >> 3) & 7, wi = tid & 7;
    const int d_ = t0d + dl, h_ = t0h + hl;
    const int w2 = t0w + wi * 2;
    const int sidx = d_ * HW + h_ * W + w2;

    // ---- ddf loads FIRST ----
    const float* dp = ddf + (size_t)b * 3 * DHW;
    float2 vd = *reinterpret_cast<const float2*>(dp + sidx);
    float2 vh = *reinterpret_cast<const float2*>(dp + DHW + sidx);
    float2 vw = *reinterpret_cast<const float2*>(dp + 2 * DHW + sidx);
    asm volatile("" ::: "memory");

    // granule g -> global offset (w-overhang clamps to W-4: affected dwords
    // lie past the max read index, never read)
    auto gsrc_off = [&](int g) {
        int row = g / GPR;
        int rw  = (g - row * GPR) * 4;
        int rd  = row / RH;
        int rh  = row - rd * RH;
        return min(lo_d + rd, D - 1) * HW + min(lo_h + rh, H - 1) * W
             + min(lo_w + rw, W - 4);
    };

    auto issue_stage = [&](const float* src) {
#pragma unroll
        for (int i = 0; i < 2; ++i) {        // 2 uniform rounds
            int g = tid + i * NT;            // < 1024 < NGR
            gload_lds16(src + gsrc_off(g), &smem[g * 4]);
        }
        if (tid < TAILN) {                   // partial-wave-safe ds_write tail
            int g = tid + 2 * NT;            // 1024..1349
            float4 v = *reinterpret_cast<const float4*>(src + gsrc_off(g));
            *reinterpret_cast<float4*>(&smem[g * 4]) = v;
        }
    };

    issue_stage(imgb);                       // ch0 in flight
    asm volatile("" ::: "memory");

    // clamped coords (persisted across both passes; 6 VGPR)
    float cds[2], chs[2], cws[2];
    cds[0] = fminf(fmaxf((float)d_ + vd.x, 0.0f), (float)(D - 1));
    cds[1] = fminf(fmaxf((float)d_ + vd.y, 0.0f), (float)(D - 1));
    chs[0] = fminf(fmaxf((float)h_ + vh.x, 0.0f), (float)(H - 1));
    chs[1] = fminf(fmaxf((float)h_ + vh.y, 0.0f), (float)(H - 1));
    cws[0] = fminf(fmaxf((float)w2 + vw.x, 0.0f), (float)(W - 1));
    cws[1] = fminf(fmaxf((float)(w2 + 1) + vw.y, 0.0f), (float)(W - 1));

    // weights/addresses computed once (persisted across both passes)
    unsigned a0[2];
    float W00[2], W01[2], W10[2], W11[2], GD[2], FD[2];
    int fb = 0;
#pragma unroll
    for (int k = 0; k < 2; ++k) {
        float cd = cds[k], ch = chs[k], cw = cws[k];
        float d0f = floorf(cd), h0f = floorf(ch), w0f = floorf(cw);
        float fd = cd - d0f, fh = ch - h0f, fw = cw - w0f;
        int d0 = (int)d0f, h0 = (int)h0f, w0 = (int)w0f;
        bool bad = (d0 < lo_d) | (d0 + 1 > hi_d)
                 | (h0 < lo_h) | (h0 + 1 > hi_h)
                 | (w0 < lo_w) | (w0 + 1 > hi_w);
        fb |= (int)bad << k;
        float gh = 1.0f - fh, gw = 1.0f - fw;
        W00[k] = gh * gw; W01[k] = gh * fw;
        W10[k] = fh * gw; W11[k] = fh * fw;
        GD[k] = 1.0f - fd; FD[k] = fd;
        int row = (d0 - lo_d) * RH + (h0 - lo_h);
        a0[k] = lds0 + (unsigned)(row * ROW_B + (w0 - lo_w) * 4);
    }

    // one pass: 8 ds_read2_b32 batched -> one wait -> FMAs; rare fixup; store
    auto do_pass = [&](const float* gimg, float* optr) {
        v2f r00[2], r01[2], r10[2], r11[2];
#pragma unroll
        for (int k = 0; k < 2; ++k) {
            unsigned a1 = a0[k] + PLANE_B;
            asm volatile("ds_read2_b32 %0, %1 offset0:0 offset1:1"
                         : "=v"(r00[k]) : "v"(a0[k]));
            asm volatile("ds_read2_b32 %0, %1 offset0:24 offset1:25"
                         : "=v"(r01[k]) : "v"(a0[k]));
            asm volatile("ds_read2_b32 %0, %1 offset0:0 offset1:1"
                         : "=v"(r10[k]) : "v"(a1));
            asm volatile("ds_read2_b32 %0, %1 offset0:24 offset1:25"
                         : "=v"(r11[k]) : "v"(a1));
        }
        asm volatile("s_waitcnt lgkmcnt(0)" ::: "memory");
        __builtin_amdgcn_sched_barrier(0);

        float acc[2];
#pragma unroll
        for (int k = 0; k < 2; ++k) {
            float p0 = r00[k].x * W00[k] + r00[k].y * W01[k]
                     + r01[k].x * W10[k] + r01[k].y * W11[k];
            float p1 = r10[k].x * W00[k] + r10[k].y * W01[k]
                     + r11[k].x * W10[k] + r11[k].y * W11[k];
            acc[k] = GD[k] * p0 + FD[k] * p1;
        }
        if (fb) {                            // rare: exact global recompute
#pragma unroll
            for (int k = 0; k < 2; ++k) {
                if (fb & (1 << k)) {
                    float cd = cds[k], ch = chs[k], cw = cws[k];
                    float d0f = floorf(cd), h0f = floorf(ch), w0f = floorf(cw);
                    float fd = cd - d0f, fh = ch - h0f, fw = cw - w0f;
                    int d0 = (int)d0f, h0 = (int)h0f, w0 = (int)w0f;
                    int d1 = min(d0 + 1, D - 1);
                    int h1 = min(h0 + 1, H - 1);
                    int w1 = min(w0 + 1, W - 1);
                    float gd = 1.0f - fd, gh = 1.0f - fh, gw = 1.0f - fw;
                    float w00 = gh * gw, w01 = gh * fw, w10 = fh * gw, w11 = fh * fw;
                    int o00 = d0 * HW + h0 * W, o01 = d0 * HW + h1 * W;
                    int o10 = d1 * HW + h0 * W, o11 = d1 * HW + h1 * W;
                    float q0 = gimg[o00 + w0] * w00 + gimg[o00 + w1] * w01
                             + gimg[o01 + w0] * w10 + gimg[o01 + w1] * w11;
                    float q1 = gimg[o10 + w0] * w00 + gimg[o10 + w1] * w01
                             + gimg[o11 + w0] * w10 + gimg[o11 + w1] * w11;
                    acc[k] = gd * q0 + fd * q1;
                }
            }
        }
        *reinterpret_cast<float2*>(optr) = make_float2(acc[0], acc[1]);
    };

    float* outb = out + (size_t)b * C * DHW;

    // ---- pass 0 ----
    asm volatile("s_waitcnt vmcnt(0) lgkmcnt(0)" ::: "memory");  // ch0 staged
    __builtin_amdgcn_s_barrier();
    do_pass(imgb, outb + sidx);

    __builtin_amdgcn_s_barrier();                       // ch0 reads done
    asm volatile("" ::: "memory");

    // ---- pass 1 ----
    issue_stage(imgb + DHW);
    asm volatile("s_waitcnt vmcnt(0) lgkmcnt(0)" ::: "memory");  // ch1 staged
    __builtin_amdgcn_s_barrier();
    do_pass(imgb + DHW, outb + DHW + sidx);
}

extern "C" void kernel_launch(void* const* d_in, const int* in_sizes, int n_in,
                              void* d_out, int out_size, void* d_ws, size_t ws_size,
                              hipStream_t stream) {
    const float* image = (const float*)d_in[0];
    const float* ddf   = (const float*)d_in[1];
    float* out = (float*)d_out;

    int grid = B * 2048;   // 16d x 16h x 8w tiles of 8x8x16 = 4096 blocks
    stn_kernel<<<grid, NT, 0, stream>>>(image, ddf, out);
}